// Round 8
// baseline (254.880 us; speedup 1.0000x reference)
//
#include <hip/hip_runtime.h>
#include <hip/hip_bf16.h>
#include <math.h>

#define N_NODES   100000
#define IN_DIM    256
#define HIDDEN    512
#define N_INC     1000000
#define N_SEG     100000
#define NHALF     50000       // node-half size (2 halves)

typedef __attribute__((ext_vector_type(8))) short bf16x8;
typedef __attribute__((ext_vector_type(4))) float f32x4;

__device__ __forceinline__ unsigned short f2bf(float f) {
  unsigned int u = __builtin_bit_cast(unsigned int, f);
  u += 0x7FFFu + ((u >> 16) & 1u);   // RNE
  return (unsigned short)(u >> 16);
}
__device__ __forceinline__ float bflo(unsigned int u) {   // low bf16 -> f32
  return __builtin_bit_cast(float, u << 16);
}
__device__ __forceinline__ float bfhi(unsigned int u) {   // high bf16 -> f32
  return __builtin_bit_cast(float, u & 0xFFFF0000u);
}
__device__ __forceinline__ unsigned pack2(float a, float b) {
  return (unsigned)f2bf(a) | ((unsigned)f2bf(b) << 16);
}

#define XBF_BLOCKS    25000   // N_NODES*64 float4s / 256 threads
#define STARTS_BLOCKS 391     // ceil((N_SEG+1)/256)
#define W1T_BLOCKS    128     // 32768 float4s / 256

// ---------------- kernel 1: fused prep (xbc | seg_starts | w1t by block role) ----------
// xbc layout: [chunk c 0..7][half h 0..1][node' 0..49999][32 dims] bf16.
// Region (c,h) = 3.2 MB — fits one XCD's 4 MB L2 when chunk is XCD-affine.
__global__ void k_prep(const float* __restrict__ x, unsigned short* __restrict__ xbc,
                       const int* __restrict__ ids, int* __restrict__ starts,
                       const float* __restrict__ W1, unsigned short* __restrict__ W1t) {
  const int b = blockIdx.x;
  const int tid = threadIdx.x;
  if (b < XBF_BLOCKS) {
    // x f32 -> xbc bf16 chunk layout
    size_t idx = (size_t)b * 256 + tid;          // one float4 each
    int n = (int)(idx >> 6);                     // node 0..99999
    int q = (int)(idx & 63);                     // float4 index within row
    float4 v = *(const float4*)(x + (size_t)n * IN_DIM + q * 4);
    int c  = q >> 3;                             // chunk 0..7 (32 dims each)
    int h  = n >= NHALF;
    int np = n - h * NHALF;
    size_t dst = ((size_t)(c * 2 + h) * NHALF + np) * 32 + (q & 7) * 4;  // ushort units
    uint2 p;
    p.x = pack2(v.x, v.y);
    p.y = pack2(v.z, v.w);
    *(uint2*)(xbc + dst) = p;
  } else if (b < XBF_BLOCKS + STARTS_BLOCKS) {
    // starts[s] = first i with ids[i] >= s (ids sorted); starts[N_SEG] = N_INC
    int s = (b - XBF_BLOCKS) * 256 + tid;
    if (s > N_SEG) return;
    int lo = 0, hi = N_INC;
    while (lo < hi) {
      int mid = (lo + hi) >> 1;
      if (ids[mid] < s) lo = mid + 1; else hi = mid;
    }
    starts[s] = lo;
  } else {
    // W1 f32[256][512] -> W1t bf16[512][256]
    int idx = (b - XBF_BLOCKS - STARTS_BLOCKS) * 256 + tid;   // 0..32767
    int k  = idx >> 7;                           // 0..255
    int c4 = idx & 127;                          // float4 index along HIDDEN
    float4 v = *(const float4*)(W1 + (size_t)k * HIDDEN + c4 * 4);
    W1t[(c4 * 4 + 0) * IN_DIM + k] = f2bf(v.x);
    W1t[(c4 * 4 + 1) * IN_DIM + k] = f2bf(v.y);
    W1t[(c4 * 4 + 2) * IN_DIM + k] = f2bf(v.z);
    W1t[(c4 * 4 + 3) * IN_DIM + k] = f2bf(v.w);
  }
}

#define ACC8(v)                                                        \
  a0 += bflo((v).x); a1 += bfhi((v).x);                                \
  a2 += bflo((v).y); a3 += bfhi((v).y);                                \
  a4 += bflo((v).z); a5 += bfhi((v).z);                                \
  a6 += bflo((v).w); a7 += bfhi((v).w);

// ---------------- kernel 2: XCD-affine chunked gather + segment sum ----------------
// chunk c = blockIdx.x & 7 (round-robin block->XCD heuristic). Each wave: 4 segments
// x 4 incidences x 4 lanes (16 B each). Two node-half passes keep the live gather
// region at 3.2 MB (< 4 MB per-XCD L2). Reduction: shfl_xor strides 4,8.
__global__ void k_segsum(const unsigned short* __restrict__ xbc, const int* __restrict__ nodes,
                         const int* __restrict__ starts, unsigned short* __restrict__ Zb) {
  const int lane = threadIdx.x & 63;
  const int wv   = threadIdx.x >> 6;           // 0..3
  const int c    = blockIdx.x & 7;             // chunk = XCD affinity
  const int grp  = blockIdx.x >> 3;            // segment group
  const int seg_slot = lane >> 4;              // 0..3
  const int inc_lane = (lane >> 2) & 3;        // 0..3
  const int dim_lane = lane & 3;               // 0..3
  const int s = (grp * 4 + wv) * 4 + seg_slot;
  int beg = 0, end = 0;
  if (s < N_SEG) { beg = starts[s]; end = starts[s + 1]; }
  float a0 = 0.f, a1 = 0.f, a2 = 0.f, a3 = 0.f;
  float a4 = 0.f, a5 = 0.f, a6 = 0.f, a7 = 0.f;
  #pragma unroll
  for (int h = 0; h < 2; ++h) {
    const int lo = h * NHALF;
    const unsigned short* base = xbc + ((size_t)(c * 2 + h) * NHALF) * 32 + dim_lane * 8;
    for (int j = beg + inc_lane; j < end; j += 4) {
      int n = nodes[j] - lo;
      if ((unsigned)n < (unsigned)NHALF) {
        uint4 v = *(const uint4*)(base + (size_t)n * 32);
        ACC8(v);
      }
    }
  }
  // reduce across inc_lane (lane bits 2-3)
  a0 += __shfl_xor(a0, 4, 64);  a0 += __shfl_xor(a0, 8, 64);
  a1 += __shfl_xor(a1, 4, 64);  a1 += __shfl_xor(a1, 8, 64);
  a2 += __shfl_xor(a2, 4, 64);  a2 += __shfl_xor(a2, 8, 64);
  a3 += __shfl_xor(a3, 4, 64);  a3 += __shfl_xor(a3, 8, 64);
  a4 += __shfl_xor(a4, 4, 64);  a4 += __shfl_xor(a4, 8, 64);
  a5 += __shfl_xor(a5, 4, 64);  a5 += __shfl_xor(a5, 8, 64);
  a6 += __shfl_xor(a6, 4, 64);  a6 += __shfl_xor(a6, 8, 64);
  a7 += __shfl_xor(a7, 4, 64);  a7 += __shfl_xor(a7, 8, 64);
  if (inc_lane == 0 && s < N_SEG) {
    uint4 p;
    p.x = pack2(a0, a1);
    p.y = pack2(a2, a3);
    p.z = pack2(a4, a5);
    p.w = pack2(a6, a7);
    *(uint4*)(Zb + (size_t)s * IN_DIM + c * 32 + dim_lane * 8) = p;
  }
}

// ---------------- kernel 3: MFMA MLP v2 — 64 rows/wave ----------------
// Block: 256 thr / 4 waves; block tile 256 rows; wave tile 64 rows x 64 cols (nt 0..7).
// A in registers (a[4][8] uint4, full K=256). Per nt: stage B 64 cols x K=256 (32 KB),
// one barrier pair, 128 MFMAs/wave; each ds_read_b128 of B feeds 4 MFMAs.
// C/D layout (m89-verified): col = lane&15, row = (lane>>4)*4 + e.
__global__ __launch_bounds__(256, 2) void k_mlp(
    const unsigned short* __restrict__ Zb, const unsigned short* __restrict__ W1t,
    const float* __restrict__ b1, const float* __restrict__ W2,
    const float* __restrict__ b2, float* __restrict__ out) {
  __shared__ __align__(16) unsigned short Bf[8][4][64][8];   // [kc][cf][lane][elem] 32 KB
  const int tid  = threadIdx.x;
  const int wave = tid >> 6;
  const int lane = tid & 63;
  const int m0   = blockIdx.x * 256 + wave * 64;

  uint4 a[4][8];
  const int arow = m0 + (lane & 15);
  const int ak   = (lane >> 4) * 8;
  #pragma unroll
  for (int kc = 0; kc < 8; ++kc) {
    #pragma unroll
    for (int rf = 0; rf < 4; ++rf) {
      int row = arow + rf * 16;
      if (row < N_SEG)
        a[rf][kc] = *(const uint4*)(Zb + (size_t)row * IN_DIM + kc * 32 + ak);
      else
        a[rf][kc] = make_uint4(0u, 0u, 0u, 0u);
    }
  }

  float logit[4][4];
  #pragma unroll
  for (int rf = 0; rf < 4; ++rf)
    #pragma unroll
    for (int e = 0; e < 4; ++e) logit[rf][e] = 0.f;

  for (int nt = 0; nt < 8; ++nt) {
    const int c0 = nt * 64;
    #pragma unroll
    for (int it = 0; it < 8; ++it) {
      int idx = it * 256 + tid;           // 0..2047
      int kc  = idx >> 8;
      int rem = idx & 255;
      int cf  = rem >> 6;
      int l2  = rem & 63;
      int col = c0 + cf * 16 + (l2 & 15);
      int kk  = kc * 32 + (l2 >> 4) * 8;
      *(uint4*)&Bf[kc][cf][l2][0] = *(const uint4*)(W1t + col * IN_DIM + kk);
    }
    __syncthreads();

    f32x4 acc[4][4];
    #pragma unroll
    for (int rf = 0; rf < 4; ++rf)
      #pragma unroll
      for (int cf = 0; cf < 4; ++cf) acc[rf][cf] = (f32x4){0.f, 0.f, 0.f, 0.f};

    #pragma unroll
    for (int kc = 0; kc < 8; ++kc) {
      #pragma unroll
      for (int cf = 0; cf < 4; ++cf) {
        bf16x8 bv = *(const bf16x8*)&Bf[kc][cf][lane][0];
        #pragma unroll
        for (int rf = 0; rf < 4; ++rf) {
          bf16x8 av = __builtin_bit_cast(bf16x8, a[rf][kc]);
          acc[rf][cf] = __builtin_amdgcn_mfma_f32_16x16x32_bf16(av, bv, acc[rf][cf], 0, 0, 0);
        }
      }
    }
    __syncthreads();

    #pragma unroll
    for (int cf = 0; cf < 4; ++cf) {
      int cc = c0 + cf * 16 + (lane & 15);
      float bb = b1[cc];
      float w2 = W2[cc];
      #pragma unroll
      for (int rf = 0; rf < 4; ++rf)
        #pragma unroll
        for (int e = 0; e < 4; ++e) {
          float h = acc[rf][cf][e] + bb;
          h = h > 0.f ? h : 0.f;
          logit[rf][e] = fmaf(h, w2, logit[rf][e]);
        }
    }
  }
  #pragma unroll
  for (int rf = 0; rf < 4; ++rf)
    #pragma unroll
    for (int e = 0; e < 4; ++e) {
      float v = logit[rf][e];
      v += __shfl_xor(v, 1, 64);
      v += __shfl_xor(v, 2, 64);
      v += __shfl_xor(v, 4, 64);
      v += __shfl_xor(v, 8, 64);
      logit[rf][e] = v;
    }
  if ((lane & 15) == 0) {
    float bb2 = b2[0];
    #pragma unroll
    for (int rf = 0; rf < 4; ++rf)
      #pragma unroll
      for (int e = 0; e < 4; ++e) {
        int row = m0 + rf * 16 + (lane >> 4) * 4 + e;
        if (row < N_SEG)
          out[row] = 1.f / (1.f + expf(-(logit[rf][e] + bb2)));
      }
  }
}

extern "C" void kernel_launch(void* const* d_in, const int* in_sizes, int n_in,
                              void* d_out, int out_size, void* d_ws, size_t ws_size,
                              hipStream_t stream) {
  const float* x   = (const float*)d_in[0];
  const int* nodes = (const int*)d_in[1];
  const int* ids   = (const int*)d_in[2];
  const float* W1  = (const float*)d_in[4];
  const float* b1  = (const float*)d_in[5];
  const float* W2  = (const float*)d_in[6];
  const float* b2  = (const float*)d_in[7];
  float* out       = (float*)d_out;

  char* ws = (char*)d_ws;
  int* starts = (int*)ws;                                        // (N_SEG+1)*4 B
  size_t off = (((size_t)(N_SEG + 1) * sizeof(int)) + 1023) & ~(size_t)1023;
  unsigned short* Zb = (unsigned short*)(ws + off);              // 51.2 MB
  off += (size_t)N_NODES * IN_DIM * sizeof(unsigned short);
  off = (off + 1023) & ~(size_t)1023;
  unsigned short* W1t = (unsigned short*)(ws + off);             // 256 KB
  off += (size_t)HIDDEN * IN_DIM * sizeof(unsigned short);
  off = (off + 1023) & ~(size_t)1023;
  unsigned short* xbc = (unsigned short*)(ws + off);             // 51.2 MB

  k_prep<<<XBF_BLOCKS + STARTS_BLOCKS + W1T_BLOCKS, 256, 0, stream>>>(
      x, xbc, ids, starts, W1, W1t);
  // grid = groups x 8 chunks; 16 segments per block (4 waves x 4 segs)
  int ngroups = (N_SEG + 15) / 16;   // 6250
  k_segsum<<<ngroups * 8, 256, 0, stream>>>(xbc, nodes, starts, Zb);
  k_mlp<<<(N_SEG + 255) / 256, 256, 0, stream>>>(Zb, W1t, b1, W2, b2, out);
}

// Round 9
// 172.417 us; speedup vs baseline: 1.4783x; 1.4783x over previous
//
#include <hip/hip_runtime.h>
#include <hip/hip_bf16.h>
#include <math.h>

#define N_NODES   100000
#define IN_DIM    256
#define HIDDEN    512
#define N_INC     1000000
#define N_SEG     100000

typedef __attribute__((ext_vector_type(8))) short bf16x8;
typedef __attribute__((ext_vector_type(4))) float f32x4;

__device__ __forceinline__ unsigned short f2bf(float f) {
  unsigned int u = __builtin_bit_cast(unsigned int, f);
  u += 0x7FFFu + ((u >> 16) & 1u);   // RNE
  return (unsigned short)(u >> 16);
}
__device__ __forceinline__ float bflo(unsigned int u) {   // low bf16 -> f32
  return __builtin_bit_cast(float, u << 16);
}
__device__ __forceinline__ float bfhi(unsigned int u) {   // high bf16 -> f32
  return __builtin_bit_cast(float, u & 0xFFFF0000u);
}
__device__ __forceinline__ unsigned pack2(float a, float b) {
  return (unsigned)f2bf(a) | ((unsigned)f2bf(b) << 16);
}

#define XBF_BLOCKS    25000   // N_NODES*IN_DIM/4 float4s / 256 threads
#define STARTS_BLOCKS 391     // ceil((N_SEG+1)/256)
#define W1T_BLOCKS    128     // 32768 float4s / 256

// ---------------- kernel 1: fused prep (xbf | seg_starts | w1t by block role) ----------
__global__ void k_prep(const float* __restrict__ x, unsigned short* __restrict__ xb,
                       const int* __restrict__ ids, int* __restrict__ starts,
                       const float* __restrict__ W1, unsigned short* __restrict__ W1t) {
  const int b = blockIdx.x;
  const int tid = threadIdx.x;
  if (b < XBF_BLOCKS) {
    // x f32 -> xb bf16 (halves gather bytes)
    size_t idx = (size_t)b * 256 + tid;          // one float4 -> uint2 each
    float4 v = *(const float4*)(x + idx * 4);
    uint2 p;
    p.x = pack2(v.x, v.y);
    p.y = pack2(v.z, v.w);
    *(uint2*)(xb + idx * 4) = p;
  } else if (b < XBF_BLOCKS + STARTS_BLOCKS) {
    // starts[s] = first i with ids[i] >= s (ids sorted); starts[N_SEG] = N_INC
    int s = (b - XBF_BLOCKS) * 256 + tid;
    if (s > N_SEG) return;
    int lo = 0, hi = N_INC;
    while (lo < hi) {
      int mid = (lo + hi) >> 1;
      if (ids[mid] < s) lo = mid + 1; else hi = mid;
    }
    starts[s] = lo;
  } else {
    // W1 f32[256][512] -> W1t bf16[512][256]
    int idx = (b - XBF_BLOCKS - STARTS_BLOCKS) * 256 + tid;   // 0..32767
    int k  = idx >> 7;                           // 0..255
    int c4 = idx & 127;                          // float4 index along HIDDEN
    float4 v = *(const float4*)(W1 + (size_t)k * HIDDEN + c4 * 4);
    W1t[(c4 * 4 + 0) * IN_DIM + k] = f2bf(v.x);
    W1t[(c4 * 4 + 1) * IN_DIM + k] = f2bf(v.y);
    W1t[(c4 * 4 + 2) * IN_DIM + k] = f2bf(v.z);
    W1t[(c4 * 4 + 3) * IN_DIM + k] = f2bf(v.w);
  }
}

// ---------------- kernel 2: gather(bf16) + segment sum -> Zb bf16 (quarter grid) --------
// Split-row: lanes 0-31 even incidences, lanes 32-63 odd; 16 B/lane (uint4) so one
// wave instruction covers TWO 512 B rows. Halves combined via shfl_xor(32).
// Launched 4x with s0 = quarter base so per-dispatch time (~19 us) stops flooding
// the rocprof top-5 (diagnostic attribution for prep/mlp).
#define ACC8(v)                                                        \
  acc0 += bflo((v).x); acc1 += bfhi((v).x);                            \
  acc2 += bflo((v).y); acc3 += bfhi((v).y);                            \
  acc4 += bflo((v).z); acc5 += bfhi((v).z);                            \
  acc6 += bflo((v).w); acc7 += bfhi((v).w);

__global__ void k_segsum(const unsigned short* __restrict__ xb, const int* __restrict__ nodes,
                         const int* __restrict__ starts, unsigned short* __restrict__ Zb,
                         int s0) {
  int wave = threadIdx.x >> 6;
  int lane = threadIdx.x & 63;
  int s = s0 + blockIdx.x * 4 + wave;
  if (s >= N_SEG) return;
  const int beg = starts[s];
  const int end = starts[s + 1];
  const int half = lane >> 5;
  const int sl   = lane & 31;
  const unsigned short* base = xb + sl * 8;    // this lane's 16B slice within any row
  float acc0 = 0.f, acc1 = 0.f, acc2 = 0.f, acc3 = 0.f;
  float acc4 = 0.f, acc5 = 0.f, acc6 = 0.f, acc7 = 0.f;
  int j = beg + half;
  for (; j + 6 < end; j += 8) {               // 4 rows per half per iter
    int n0 = nodes[j], n1 = nodes[j + 2], n2 = nodes[j + 4], n3 = nodes[j + 6];
    uint4 v0 = *(const uint4*)(base + (size_t)n0 * IN_DIM);
    uint4 v1 = *(const uint4*)(base + (size_t)n1 * IN_DIM);
    uint4 v2 = *(const uint4*)(base + (size_t)n2 * IN_DIM);
    uint4 v3 = *(const uint4*)(base + (size_t)n3 * IN_DIM);
    ACC8(v0); ACC8(v1); ACC8(v2); ACC8(v3);
  }
  for (; j < end; j += 2) {
    int n0 = nodes[j];
    uint4 v0 = *(const uint4*)(base + (size_t)n0 * IN_DIM);
    ACC8(v0);
  }
  acc0 += __shfl_xor(acc0, 32, 64);
  acc1 += __shfl_xor(acc1, 32, 64);
  acc2 += __shfl_xor(acc2, 32, 64);
  acc3 += __shfl_xor(acc3, 32, 64);
  acc4 += __shfl_xor(acc4, 32, 64);
  acc5 += __shfl_xor(acc5, 32, 64);
  acc6 += __shfl_xor(acc6, 32, 64);
  acc7 += __shfl_xor(acc7, 32, 64);
  if (half == 0) {
    uint4 p;
    p.x = pack2(acc0, acc1);
    p.y = pack2(acc2, acc3);
    p.z = pack2(acc4, acc5);
    p.w = pack2(acc6, acc7);
    *(uint4*)(Zb + (size_t)s * IN_DIM + sl * 8) = p;
  }
}

// ---------------- kernel 3: MFMA MLP v2 — 64 rows/wave ----------------
// Block: 256 thr / 4 waves; block tile 256 rows; wave tile 64 rows x 64 cols (nt 0..7).
// A in registers (a[4][8] uint4, full K=256). Per nt: stage B 64 cols x K=256 (32 KB),
// one barrier pair, 128 MFMAs/wave; each ds_read_b128 of B feeds 4 MFMAs.
// C/D layout (m89-verified): col = lane&15, row = (lane>>4)*4 + e.
__global__ __launch_bounds__(256, 2) void k_mlp(
    const unsigned short* __restrict__ Zb, const unsigned short* __restrict__ W1t,
    const float* __restrict__ b1, const float* __restrict__ W2,
    const float* __restrict__ b2, float* __restrict__ out) {
  __shared__ __align__(16) unsigned short Bf[8][4][64][8];   // [kc][cf][lane][elem] 32 KB
  const int tid  = threadIdx.x;
  const int wave = tid >> 6;
  const int lane = tid & 63;
  const int m0   = blockIdx.x * 256 + wave * 64;

  uint4 a[4][8];
  const int arow = m0 + (lane & 15);
  const int ak   = (lane >> 4) * 8;
  #pragma unroll
  for (int kc = 0; kc < 8; ++kc) {
    #pragma unroll
    for (int rf = 0; rf < 4; ++rf) {
      int row = arow + rf * 16;
      if (row < N_SEG)
        a[rf][kc] = *(const uint4*)(Zb + (size_t)row * IN_DIM + kc * 32 + ak);
      else
        a[rf][kc] = make_uint4(0u, 0u, 0u, 0u);
    }
  }

  float logit[4][4];
  #pragma unroll
  for (int rf = 0; rf < 4; ++rf)
    #pragma unroll
    for (int e = 0; e < 4; ++e) logit[rf][e] = 0.f;

  for (int nt = 0; nt < 8; ++nt) {
    const int c0 = nt * 64;
    #pragma unroll
    for (int it = 0; it < 8; ++it) {
      int idx = it * 256 + tid;           // 0..2047
      int kc  = idx >> 8;
      int rem = idx & 255;
      int cf  = rem >> 6;
      int l2  = rem & 63;
      int col = c0 + cf * 16 + (l2 & 15);
      int kk  = kc * 32 + (l2 >> 4) * 8;
      *(uint4*)&Bf[kc][cf][l2][0] = *(const uint4*)(W1t + col * IN_DIM + kk);
    }
    __syncthreads();

    f32x4 acc[4][4];
    #pragma unroll
    for (int rf = 0; rf < 4; ++rf)
      #pragma unroll
      for (int cf = 0; cf < 4; ++cf) acc[rf][cf] = (f32x4){0.f, 0.f, 0.f, 0.f};

    #pragma unroll
    for (int kc = 0; kc < 8; ++kc) {
      #pragma unroll
      for (int cf = 0; cf < 4; ++cf) {
        bf16x8 bv = *(const bf16x8*)&Bf[kc][cf][lane][0];
        #pragma unroll
        for (int rf = 0; rf < 4; ++rf) {
          bf16x8 av = __builtin_bit_cast(bf16x8, a[rf][kc]);
          acc[rf][cf] = __builtin_amdgcn_mfma_f32_16x16x32_bf16(av, bv, acc[rf][cf], 0, 0, 0);
        }
      }
    }
    __syncthreads();

    #pragma unroll
    for (int cf = 0; cf < 4; ++cf) {
      int cc = c0 + cf * 16 + (lane & 15);
      float bb = b1[cc];
      float w2 = W2[cc];
      #pragma unroll
      for (int rf = 0; rf < 4; ++rf)
        #pragma unroll
        for (int e = 0; e < 4; ++e) {
          float h = acc[rf][cf][e] + bb;
          h = h > 0.f ? h : 0.f;
          logit[rf][e] = fmaf(h, w2, logit[rf][e]);
        }
    }
  }
  #pragma unroll
  for (int rf = 0; rf < 4; ++rf)
    #pragma unroll
    for (int e = 0; e < 4; ++e) {
      float v = logit[rf][e];
      v += __shfl_xor(v, 1, 64);
      v += __shfl_xor(v, 2, 64);
      v += __shfl_xor(v, 4, 64);
      v += __shfl_xor(v, 8, 64);
      logit[rf][e] = v;
    }
  if ((lane & 15) == 0) {
    float bb2 = b2[0];
    #pragma unroll
    for (int rf = 0; rf < 4; ++rf)
      #pragma unroll
      for (int e = 0; e < 4; ++e) {
        int row = m0 + rf * 16 + (lane >> 4) * 4 + e;
        if (row < N_SEG)
          out[row] = 1.f / (1.f + expf(-(logit[rf][e] + bb2)));
      }
  }
}

extern "C" void kernel_launch(void* const* d_in, const int* in_sizes, int n_in,
                              void* d_out, int out_size, void* d_ws, size_t ws_size,
                              hipStream_t stream) {
  const float* x   = (const float*)d_in[0];
  const int* nodes = (const int*)d_in[1];
  const int* ids   = (const int*)d_in[2];
  const float* W1  = (const float*)d_in[4];
  const float* b1  = (const float*)d_in[5];
  const float* W2  = (const float*)d_in[6];
  const float* b2  = (const float*)d_in[7];
  float* out       = (float*)d_out;

  char* ws = (char*)d_ws;
  int* starts = (int*)ws;                                        // (N_SEG+1)*4 B
  size_t off = (((size_t)(N_SEG + 1) * sizeof(int)) + 1023) & ~(size_t)1023;
  unsigned short* Zb = (unsigned short*)(ws + off);              // 51.2 MB
  off += (size_t)N_NODES * IN_DIM * sizeof(unsigned short);
  off = (off + 1023) & ~(size_t)1023;
  unsigned short* W1t = (unsigned short*)(ws + off);             // 256 KB
  off += (size_t)HIDDEN * IN_DIM * sizeof(unsigned short);
  off = (off + 1023) & ~(size_t)1023;
  unsigned short* xb = (unsigned short*)(ws + off);              // 51.2 MB

  k_prep<<<XBF_BLOCKS + STARTS_BLOCKS + W1T_BLOCKS, 256, 0, stream>>>(
      x, xb, ids, starts, W1, W1t);
  // 4 quarter dispatches (25000 segments each -> 6250 blocks)
  for (int q = 0; q < 4; ++q)
    k_segsum<<<6250, 256, 0, stream>>>(xb, nodes, starts, Zb, q * 25000);
  k_mlp<<<(N_SEG + 255) / 256, 256, 0, stream>>>(Zb, W1t, b1, W2, b2, out);
}